// Round 2
// baseline (226.042 us; speedup 1.0000x reference)
//
#include <hip/hip_runtime.h>

typedef __attribute__((ext_vector_type(8))) short short8;
typedef __attribute__((ext_vector_type(4))) float floatx4;
typedef __attribute__((ext_vector_type(4))) unsigned short ushortx4;

#define MFMA_BF16(A, Bv, C) __builtin_amdgcn_mfma_f32_16x16x32_bf16(A, Bv, C, 0, 0, 0)

#if __has_builtin(__builtin_amdgcn_exp2f)
#define EXP2(x) __builtin_amdgcn_exp2f(x)
#else
#define EXP2(x) exp2f(x)
#endif

__device__ __forceinline__ unsigned short f2bf(float f) {  // RNE
  unsigned int u = __builtin_bit_cast(unsigned int, f);
  u += 0x7FFFu + ((u >> 16) & 1u);
  return (unsigned short)(u >> 16);
}
__device__ __forceinline__ unsigned short f2bf_trunc(float f) {  // cheap, bias cancels in P/l ratio
  return (unsigned short)(__builtin_bit_cast(unsigned int, f) >> 16);
}

// Prep: blocks 0-511 convert K fp32->bf16; blocks 512-1023 transpose V -> Vt[b][d][s] bf16.
__global__ __launch_bounds__(256) void prep_kv(
    const float* __restrict__ k, const float* __restrict__ v,
    unsigned short* __restrict__ kb, unsigned short* __restrict__ vt) {
  __shared__ float tile[64 * 68];
  int blk = blockIdx.x;
  int t = threadIdx.x;
  if (blk < 512) {
    size_t base = (size_t)blk * 4096 + t * 4;
#pragma unroll
    for (int i = 0; i < 4; i++) {
      size_t off = base + (size_t)i * 1024;
      floatx4 f = *(const floatx4*)(k + off);
      ushortx4 h;
      h[0] = f2bf(f[0]); h[1] = f2bf(f[1]); h[2] = f2bf(f[2]); h[3] = f2bf(f[3]);
      *(ushortx4*)(kb + off) = h;
    }
  } else {
    blk -= 512;
    int b = blk >> 6, si = blk & 63;
    int r = t >> 2, c4 = (t & 3) * 16;
    const float* vp = v + ((size_t)b * 4096 + si * 64 + r) * 64 + c4;
#pragma unroll
    for (int i = 0; i < 4; i++)
      *(floatx4*)(tile + r * 68 + c4 + i * 4) = *(const floatx4*)(vp + i * 4);
    __syncthreads();
    unsigned short* vo = vt + ((size_t)b * 64 + r) * 4096 + si * 64 + c4;
#pragma unroll
    for (int i = 0; i < 4; i++) {
      ushortx4 h;
#pragma unroll
      for (int j = 0; j < 4; j++) h[j] = f2bf(tile[(c4 + i * 4 + j) * 68 + r]);
      *(ushortx4*)(vo + i * 4) = h;
    }
  }
}

// Attention: 512 blocks x 512 threads (8 waves). Wave = (qhalf, keygroup):
// owns 32 q-rows, processes every 4th 32-key chunk. No barriers in hot loop.
// Q converted in-kernel (block-private tile). l via ones-MFMA.
__global__ __launch_bounds__(512, 4) void attn(
    const float* __restrict__ q, const unsigned short* __restrict__ kb,
    const unsigned short* __restrict__ vt, const float* __restrict__ mask,
    float* __restrict__ out) {
  __shared__ __align__(16) char smem[20480];  // loop: 8 waves x 2560B P; epilogue: 17664B
  const int tid = threadIdx.x;
  const int wave = tid >> 6, lane = tid & 63;
  const int c = lane & 15, quad = lane >> 4;
  const int qh = wave & 1, kg = wave >> 1;
  const int b = blockIdx.x & 7, qt = blockIdx.x >> 3;  // blk%8=batch -> per-XCD K/V L2 locality
  const int q0 = qt * 64;

  const unsigned short* kB = kb + (size_t)b * 4096 * 64;
  const unsigned short* vB = vt + (size_t)b * 64 * 4096;

  // Q A-frags: fp32 load + fold (1/sqrt(64))*log2(e) so scores are log2-domain
  const float qscale = 0.18033688011112042f;
  short8 qf[2][2];
#pragma unroll
  for (int mt = 0; mt < 2; mt++)
#pragma unroll
    for (int ks = 0; ks < 2; ks++) {
      const float* qp = q + ((size_t)b * 4096 + q0 + qh * 32 + mt * 16 + c) * 64 + ks * 32 + quad * 8;
      floatx4 f0 = *(const floatx4*)qp;
      floatx4 f1 = *(const floatx4*)(qp + 4);
      short8 s;
#pragma unroll
      for (int j = 0; j < 4; j++) {
        s[j] = (short)f2bf(f0[j] * qscale);
        s[4 + j] = (short)f2bf(f1[j] * qscale);
      }
      qf[mt][ks] = s;
    }

  floatx4 o[2][4], ol[2];
#pragma unroll
  for (int mt = 0; mt < 2; mt++) {
    ol[mt] = (floatx4){0.f, 0.f, 0.f, 0.f};
#pragma unroll
    for (int dt = 0; dt < 4; dt++) o[mt][dt] = (floatx4){0.f, 0.f, 0.f, 0.f};
  }

  short8 ones;  // all-ones B: every C column = row-sum (free l)
#pragma unroll
  for (int j = 0; j < 8; j++) ones[j] = (short)0x3F80;

  char* pbase = smem + wave * 2560;              // P: [32 rows][stride 80B]
  char* pw = pbase + quad * 320 + c * 2;         // + mt*1280 + r*80 + nt*32
  const char* prd = pbase + c * 80 + quad * 16;  // + mt*1280 (b128 A-frag)

  for (int t = kg; t < 128; t += 4) {
    const int key0 = t * 32;
    short8 kf[2][2], vf[4];
#pragma unroll
    for (int nt = 0; nt < 2; nt++)
#pragma unroll
      for (int ks = 0; ks < 2; ks++)
        kf[nt][ks] = *(const short8*)(kB + (key0 + nt * 16 + c) * 64 + ks * 32 + quad * 8);
#pragma unroll
    for (int dt = 0; dt < 4; dt++)
      vf[dt] = *(const short8*)(vB + (dt * 16 + c) * 4096 + key0 + quad * 8);

    // S = Q*K^T (log2 domain); P = exp2(S) -> LDS (C-layout -> row-major, trunc-to-bf16)
#pragma unroll
    for (int mt = 0; mt < 2; mt++)
#pragma unroll
      for (int nt = 0; nt < 2; nt++) {
        floatx4 s = (floatx4){0.f, 0.f, 0.f, 0.f};
        s = MFMA_BF16(qf[mt][0], kf[nt][0], s);
        s = MFMA_BF16(qf[mt][1], kf[nt][1], s);
#pragma unroll
        for (int r = 0; r < 4; r++)
          *(unsigned short*)(pw + mt * 1280 + r * 80 + nt * 32) = f2bf_trunc(EXP2(s[r]));
      }

    // O += P*V ; l += P*ones. P read back in A-layout (b128).
#pragma unroll
    for (int mt = 0; mt < 2; mt++) {
      short8 pf = *(const short8*)(prd + mt * 1280);
#pragma unroll
      for (int dt = 0; dt < 4; dt++) o[mt][dt] = MFMA_BF16(pf, vf[dt], o[mt][dt]);
      ol[mt] = MFMA_BF16(pf, ones, ol[mt]);
    }
  }

  // Merge 8 wave-partials: kg==0 waves store, others atomicAdd (plain sums, no max state).
  __syncthreads();
  float* obuf = (float*)smem;            // [64][68]
  float* lbuf = (float*)(smem + 17408);  // [64]
  const int orow0 = qh * 32;
  if (kg == 0) {
#pragma unroll
    for (int mt = 0; mt < 2; mt++) {
#pragma unroll
      for (int dt = 0; dt < 4; dt++)
#pragma unroll
        for (int r = 0; r < 4; r++)
          obuf[(orow0 + mt * 16 + quad * 4 + r) * 68 + dt * 16 + c] = o[mt][dt][r];
      if (c == 0)
#pragma unroll
        for (int r = 0; r < 4; r++)
          lbuf[orow0 + mt * 16 + quad * 4 + r] = ol[mt][r];
    }
  }
  __syncthreads();
  if (kg != 0) {
#pragma unroll
    for (int mt = 0; mt < 2; mt++) {
#pragma unroll
      for (int dt = 0; dt < 4; dt++)
#pragma unroll
        for (int r = 0; r < 4; r++)
          atomicAdd(&obuf[(orow0 + mt * 16 + quad * 4 + r) * 68 + dt * 16 + c], o[mt][dt][r]);
      if (c == 0)
#pragma unroll
        for (int r = 0; r < 4; r++)
          atomicAdd(&lbuf[orow0 + mt * 16 + quad * 4 + r], ol[mt][r]);
    }
  }
  __syncthreads();

  // out = O/l * mask, coalesced float4 stores (512 threads: 8 floats each)
  const int row = tid >> 3, dg = (tid & 7) * 8;
  float sc = mask[b * 4096 + q0 + row] / lbuf[row];
  float* op = out + ((size_t)b * 4096 + q0 + row) * 64 + dg;
  floatx4 a0 = *(const floatx4*)(obuf + row * 68 + dg);
  floatx4 a1 = *(const floatx4*)(obuf + row * 68 + dg + 4);
  *(floatx4*)op = a0 * sc;
  *(floatx4*)(op + 4) = a1 * sc;
}

extern "C" void kernel_launch(void* const* d_in, const int* in_sizes, int n_in,
                              void* d_out, int out_size, void* d_ws, size_t ws_size,
                              hipStream_t stream) {
  const float* q = (const float*)d_in[0];
  const float* k = (const float*)d_in[1];
  const float* v = (const float*)d_in[2];
  const float* mask = (const float*)d_in[3];
  unsigned short* kb = (unsigned short*)d_ws;  // 4 MB
  unsigned short* vt = kb + 8 * 4096 * 64;     // 4 MB (needs ws >= 8 MB)
  prep_kv<<<1024, 256, 0, stream>>>(k, v, kb, vt);
  attn<<<512, 512, 0, stream>>>(q, kb, vt, mask, (float*)d_out);
}

// Round 3
// 140.075 us; speedup vs baseline: 1.6137x; 1.6137x over previous
//
#include <hip/hip_runtime.h>

typedef __attribute__((ext_vector_type(8))) short short8;
typedef __attribute__((ext_vector_type(4))) float floatx4;
typedef __attribute__((ext_vector_type(4))) unsigned short ushortx4;
typedef unsigned int u32;

#define MFMA_BF16(A, Bv, C) __builtin_amdgcn_mfma_f32_16x16x32_bf16(A, Bv, C, 0, 0, 0)

#if __has_builtin(__builtin_amdgcn_exp2f)
#define EXP2(x) __builtin_amdgcn_exp2f(x)
#else
#define EXP2(x) exp2f(x)
#endif

__device__ __forceinline__ unsigned short f2bf(float f) {  // RNE
  unsigned int u = __builtin_bit_cast(unsigned int, f);
  u += 0x7FFFu + ((u >> 16) & 1u);
  return (unsigned short)(u >> 16);
}
__device__ __forceinline__ unsigned short f2bf_trunc(float f) {  // bias cancels in P/l ratio
  return (unsigned short)(__builtin_bit_cast(unsigned int, f) >> 16);
}
// async 16B/lane global->LDS: lds dst = uniform base + lane*16
__device__ __forceinline__ void load_lds16(const void* g, void* l) {
  __builtin_amdgcn_global_load_lds((const __attribute__((address_space(1))) u32*)g,
                                   (__attribute__((address_space(3))) u32*)l, 16, 0, 0);
}

// Prep: blocks 0-511 convert K fp32->bf16; blocks 512-1023 transpose V -> Vt[b][d][s] bf16.
__global__ __launch_bounds__(256) void prep_kv(
    const float* __restrict__ k, const float* __restrict__ v,
    unsigned short* __restrict__ kb, unsigned short* __restrict__ vt) {
  __shared__ float tile[64 * 68];
  int blk = blockIdx.x;
  int t = threadIdx.x;
  if (blk < 512) {
    size_t base = (size_t)blk * 4096 + t * 4;
#pragma unroll
    for (int i = 0; i < 4; i++) {
      size_t off = base + (size_t)i * 1024;
      floatx4 f = *(const floatx4*)(k + off);
      ushortx4 h;
      h[0] = f2bf(f[0]); h[1] = f2bf(f[1]); h[2] = f2bf(f[2]); h[3] = f2bf(f[3]);
      *(ushortx4*)(kb + off) = h;
    }
  } else {
    blk -= 512;
    int b = blk >> 6, si = blk & 63;
    int r = t >> 2, c4 = (t & 3) * 16;
    const float* vp = v + ((size_t)b * 4096 + si * 64 + r) * 64 + c4;
#pragma unroll
    for (int i = 0; i < 4; i++)
      *(floatx4*)(tile + r * 68 + c4 + i * 4) = *(const floatx4*)(vp + i * 4);
    __syncthreads();
    unsigned short* vo = vt + ((size_t)b * 64 + r) * 4096 + si * 64 + c4;
#pragma unroll
    for (int i = 0; i < 4; i++) {
      ushortx4 h;
#pragma unroll
      for (int j = 0; j < 4; j++) h[j] = f2bf(tile[(c4 + i * 4 + j) * 68 + r]);
      *(ushortx4*)(vo + i * 4) = h;
    }
  }
}

// Attention: 512 blocks x 256 thr (4 waves). Wave w owns q-rows [q0+w*16, +16) for ALL keys
// (no merge). 64-key chunks double-buffered in LDS via async global_load_lds; XOR-16B-swizzled
// layout makes both staging (dense) and fragment reads (scattered) conflict-minimal.
__global__ __launch_bounds__(256, 2) void attn(
    const float* __restrict__ q, const unsigned short* __restrict__ kb,
    const unsigned short* __restrict__ vt, const float* __restrict__ mask,
    float* __restrict__ out) {
  // elements (ushort): buf{0,1}: K[4096] V[4096]; P: 16384 + wave*1024  (40960 B total)
  __shared__ __align__(16) unsigned short smem[20480];
  const int tid = threadIdx.x;
  const int wave = tid >> 6, lane = tid & 63;
  const int c = lane & 15, quad = lane >> 4;
  const int b = blockIdx.x & 7, qt = blockIdx.x >> 3;  // blk%8=batch -> per-XCD K/V L2 locality
  const int q0 = qt * 64;

  const unsigned short* kB = kb + (size_t)b * (4096 * 64);
  const unsigned short* vB = vt + (size_t)b * (64 * 4096);

  // Q A-frags (A[m=c][k=quad*8+j]), fp32 -> bf16 with (1/8)*log2(e) folded (log2-domain scores)
  const float qscale = 0.18033688011112042f;
  short8 qf[2];
  {
    const float* qp = q + ((size_t)b * 4096 + q0 + wave * 16 + c) * 64;
#pragma unroll
    for (int ks = 0; ks < 2; ks++) {
      floatx4 f0 = *(const floatx4*)(qp + ks * 32 + quad * 8);
      floatx4 f1 = *(const floatx4*)(qp + ks * 32 + quad * 8 + 4);
      short8 s;
#pragma unroll
      for (int j = 0; j < 4; j++) {
        s[j] = (short)f2bf(f0[j] * qscale);
        s[4 + j] = (short)f2bf(f1[j] * qscale);
      }
      qf[ks] = s;
    }
  }

  floatx4 o[4], ol;
#pragma unroll
  for (int dt = 0; dt < 4; dt++) o[dt] = (floatx4){0.f, 0.f, 0.f, 0.f};
  ol = (floatx4){0.f, 0.f, 0.f, 0.f};

  short8 ones;  // B=ones => every C column = row-sum (free l)
#pragma unroll
  for (int j = 0; j < 8; j++) ones[j] = (short)0x3F80;

  const int r8 = lane >> 3, cs = lane & 7;  // staging: lane -> (row-in-chunk, 16B colslot)
  unsigned short* Pw = smem + 16384 + wave * 1024;
  const int cl = c & 7;  // fragment-read swizzle key (row & 7 == c & 7 for our reads)

  // ---- staging (async, fire-and-forget until barrier) ----
  auto stage = [&](int t, int buf) {
    const int key0 = t * 64;
    unsigned short* ldsK = smem + buf * 8192;
    unsigned short* ldsV = ldsK + 4096;
    const unsigned short* gK = kB + (size_t)key0 * 64;
#pragma unroll
    for (int i = 0; i < 2; i++) {
      const int rows0 = (i * 4 + wave) * 8;  // wave-uniform
      // K rows are contiguous in kb; source col swizzled by row&7 (= r8 since rows0%8==0)
      load_lds16(gK + (rows0 + r8) * 64 + (cs ^ r8) * 8, ldsK + rows0 * 64);
      // V: d-row (rows0+r8) of Vt, 64-key window, same swizzle
      load_lds16(vB + (size_t)(rows0 + r8) * 4096 + key0 + (cs ^ r8) * 8, ldsV + rows0 * 64);
    }
  };

  stage(0, 0);
  __syncthreads();

  for (int t = 0; t < 64; t++) {
    if (t + 1 < 64) stage(t + 1, (t + 1) & 1);

    const unsigned short* ldsK = smem + (t & 1) * 8192;
    const unsigned short* ldsV = ldsK + 4096;

    // fragments from swizzled LDS: chunkcol = (base+quad) ^ (row&7)
    short8 kf[4][2], vf[2][4];
#pragma unroll
    for (int nt = 0; nt < 4; nt++)
#pragma unroll
      for (int ks = 0; ks < 2; ks++)
        kf[nt][ks] = *(const short8*)(ldsK + (nt * 16 + c) * 64 + (((ks * 4 + quad) ^ cl) * 8));
#pragma unroll
    for (int kc = 0; kc < 2; kc++)
#pragma unroll
      for (int dt = 0; dt < 4; dt++)
        vf[kc][dt] = *(const short8*)(ldsV + (dt * 16 + c) * 64 + (((kc * 4 + quad) ^ cl) * 8));

    // S = Q*K^T (log2 domain); P = exp2(S) -> per-wave LDS region in A-linear order
#pragma unroll
    for (int nt = 0; nt < 4; nt++) {
      floatx4 s = (floatx4){0.f, 0.f, 0.f, 0.f};
      s = MFMA_BF16(qf[0], kf[nt][0], s);
      s = MFMA_BF16(qf[1], kf[nt][1], s);
#pragma unroll
      for (int r = 0; r < 4; r++) {
        // element index for P[q=quad*4+r][k=nt*16+c] in A-linear layout
        Pw[(nt >> 1) * 512 + ((nt & 1) * 2 + (c >> 3)) * 128 + (quad * 4 + r) * 8 + (c & 7)] =
            f2bf_trunc(EXP2(s[r]));
      }
    }

    // O += P*V ; l += P*ones  (P A-frags are lane-linear b128 reads: conflict-free)
#pragma unroll
    for (int kc = 0; kc < 2; kc++) {
      short8 pf = *(const short8*)(Pw + kc * 512 + lane * 8);
#pragma unroll
      for (int dt = 0; dt < 4; dt++) o[dt] = MFMA_BF16(pf, vf[kc][dt], o[dt]);
      ol = MFMA_BF16(pf, ones, ol);
    }

    __syncthreads();  // drains prefetch + protects buffer reuse
  }

  // Epilogue: all state in-register, direct stores. C-layout: row=quad*4+r, col=c.
#pragma unroll
  for (int r = 0; r < 4; r++) {
    const int row = q0 + wave * 16 + quad * 4 + r;
    const float sc = mask[b * 4096 + row] / ol[r];
    float* op = out + ((size_t)b * 4096 + row) * 64 + c;
#pragma unroll
    for (int dt = 0; dt < 4; dt++) op[dt * 16] = o[dt][r] * sc;
  }
}

extern "C" void kernel_launch(void* const* d_in, const int* in_sizes, int n_in,
                              void* d_out, int out_size, void* d_ws, size_t ws_size,
                              hipStream_t stream) {
  const float* q = (const float*)d_in[0];
  const float* k = (const float*)d_in[1];
  const float* v = (const float*)d_in[2];
  const float* mask = (const float*)d_in[3];
  unsigned short* kb = (unsigned short*)d_ws;  // 4 MB
  unsigned short* vt = kb + 8 * 4096 * 64;     // 4 MB (needs ws >= 8 MB)
  prep_kv<<<1024, 256, 0, stream>>>(k, v, kb, vt);
  attn<<<512, 256, 0, stream>>>(q, kb, vt, mask, (float*)d_out);
}